// Round 13
// baseline (1275.111 us; speedup 1.0000x reference)
//
#include <hip/hip_runtime.h>

// Problem constants
#define NR   300
#define NB   4
#define NN   512
#define TT   2048          // NB*NN
#define CH   30            // region-row stride (persistent blocks)
#define NCH  10            // regions per block
#define SLC  8             // k-slice blocks per region (64 cols each)

#define TAU   0.8f
#define OMT   0.2f         // 1-TAU
#define ALPH  0.05f
#define OMA   0.95f
#define LRQ   5.0e-6f      // HEBB_LR / B = 2e-5/4
#define NSC   0.02f

#define SENT  0xFFFFFFFFu  // delta sentinel (negative qNaN; vs-vsi always finite)

// padded LDS x layout: [b][quarter][128] with quarter stride 136 floats
#define QSTR 136
#define BSTR 544           // 4*136
__device__ __forceinline__ int xidx(int b, int n) {
    return b * BSTR + (n >> 7) * QSTR + (n & 127);
}

// Force a value to be materialized in a VGPR *here* (defeats load-sinking).
__device__ __forceinline__ void pin(float& x) { asm volatile("" : "+v"(x)); }

// ---- TWO-STREAM sentinel poll, fully self-contained in one asm block.
// Stream buffers are hard-clobbered v[32:47] (never C++-visible -> no
// spill-before-wait hazard, R8 lesson). Streams staggered ~RT/2 by s_sleep.
__device__ __forceinline__ void poll8_2s(const float* p0, const float* p1,
                                         float& o0, float& o1, float& o2, float& o3,
                                         float& o4, float& o5, float& o6, float& o7) {
    unsigned long long sacc;
    asm volatile(
        "global_load_dwordx4 v[32:35], %9, off sc0 sc1\n\t"
        "global_load_dwordx4 v[36:39], %10, off sc0 sc1\n\t"
        "s_sleep 5\n\t"
        "global_load_dwordx4 v[40:43], %9, off sc0 sc1\n\t"
        "global_load_dwordx4 v[44:47], %10, off sc0 sc1\n\t"
        "Lpoll_%=:\n\t"
        "s_waitcnt vmcnt(2)\n\t"
        "v_cmp_ne_u32 vcc, -1, v32\n\t"
        "s_mov_b64 %8, vcc\n\t"
        "v_cmp_ne_u32 vcc, -1, v33\n\t"
        "s_and_b64 %8, %8, vcc\n\t"
        "v_cmp_ne_u32 vcc, -1, v34\n\t"
        "s_and_b64 %8, %8, vcc\n\t"
        "v_cmp_ne_u32 vcc, -1, v35\n\t"
        "s_and_b64 %8, %8, vcc\n\t"
        "v_cmp_ne_u32 vcc, -1, v36\n\t"
        "s_and_b64 %8, %8, vcc\n\t"
        "v_cmp_ne_u32 vcc, -1, v37\n\t"
        "s_and_b64 %8, %8, vcc\n\t"
        "v_cmp_ne_u32 vcc, -1, v38\n\t"
        "s_and_b64 %8, %8, vcc\n\t"
        "v_cmp_ne_u32 vcc, -1, v39\n\t"
        "s_and_b64 %8, %8, vcc\n\t"
        "s_cmp_eq_u64 %8, exec\n\t"
        "s_cbranch_scc1 Ldone0_%=\n\t"
        "global_load_dwordx4 v[32:35], %9, off sc0 sc1\n\t"
        "global_load_dwordx4 v[36:39], %10, off sc0 sc1\n\t"
        "s_waitcnt vmcnt(2)\n\t"
        "v_cmp_ne_u32 vcc, -1, v40\n\t"
        "s_mov_b64 %8, vcc\n\t"
        "v_cmp_ne_u32 vcc, -1, v41\n\t"
        "s_and_b64 %8, %8, vcc\n\t"
        "v_cmp_ne_u32 vcc, -1, v42\n\t"
        "s_and_b64 %8, %8, vcc\n\t"
        "v_cmp_ne_u32 vcc, -1, v43\n\t"
        "s_and_b64 %8, %8, vcc\n\t"
        "v_cmp_ne_u32 vcc, -1, v44\n\t"
        "s_and_b64 %8, %8, vcc\n\t"
        "v_cmp_ne_u32 vcc, -1, v45\n\t"
        "s_and_b64 %8, %8, vcc\n\t"
        "v_cmp_ne_u32 vcc, -1, v46\n\t"
        "s_and_b64 %8, %8, vcc\n\t"
        "v_cmp_ne_u32 vcc, -1, v47\n\t"
        "s_and_b64 %8, %8, vcc\n\t"
        "s_cmp_eq_u64 %8, exec\n\t"
        "s_cbranch_scc1 Ldone1_%=\n\t"
        "global_load_dwordx4 v[40:43], %9, off sc0 sc1\n\t"
        "global_load_dwordx4 v[44:47], %10, off sc0 sc1\n\t"
        "s_branch Lpoll_%=\n\t"
        "Ldone1_%=:\n\t"
        "s_waitcnt vmcnt(0)\n\t"
        "v_mov_b32 v32, v40\n\t"
        "v_mov_b32 v33, v41\n\t"
        "v_mov_b32 v34, v42\n\t"
        "v_mov_b32 v35, v43\n\t"
        "v_mov_b32 v36, v44\n\t"
        "v_mov_b32 v37, v45\n\t"
        "v_mov_b32 v38, v46\n\t"
        "v_mov_b32 v39, v47\n\t"
        "Ldone0_%=:\n\t"
        "s_waitcnt vmcnt(0)\n\t"
        "v_mov_b32 %0, v32\n\t"
        "v_mov_b32 %1, v33\n\t"
        "v_mov_b32 %2, v34\n\t"
        "v_mov_b32 %3, v35\n\t"
        "v_mov_b32 %4, v36\n\t"
        "v_mov_b32 %5, v37\n\t"
        "v_mov_b32 %6, v38\n\t"
        "v_mov_b32 %7, v39"
        : "=v"(o0), "=v"(o1), "=v"(o2), "=v"(o3),
          "=v"(o4), "=v"(o5), "=v"(o6), "=v"(o7), "=&s"(sacc)
        : "v"(p0), "v"(p1)
        : "vcc", "memory",
          "v32","v33","v34","v35","v36","v37","v38","v39",
          "v40","v41","v42","v43","v44","v45","v46","v47");
}

// ---------------- v_init = v_s0 + 0.02*noise ----------------
__global__ __launch_bounds__(256) void k_init(const float* __restrict__ vs0,
                                              const float* __restrict__ noise,
                                              float* __restrict__ v_init) {
    int idx = blockIdx.x * 256 + threadIdx.x;           // float4 index
    const float4* a = (const float4*)vs0;
    const float4* b = (const float4*)noise;
    float4* o = (float4*)v_init;
    float4 va = a[idx], vb = b[idx];
    float4 r;
    r.x = va.x + NSC * vb.x; r.y = va.y + NSC * vb.y;
    r.z = va.z + NSC * vb.z; r.w = va.w + NSC * vb.w;
    o[idx] = r;
}

// ---------------- X[i,t] = inp[i,t] + sum_j A[j,i]*v_init[j,t] ----------------
__global__ __launch_bounds__(256) void k_base(const float* __restrict__ A,
                                              const float* __restrict__ v_init,
                                              const float* __restrict__ inp,
                                              float* __restrict__ X) {
    const int i0 = (blockIdx.x >> 1) * 5;
    const int t4 = (blockIdx.x & 1) * 256 + threadIdx.x;   // float4 index 0..511
    float4 acc[5];
#pragma unroll
    for (int g = 0; g < 5; g++) acc[g] = make_float4(0.f, 0.f, 0.f, 0.f);
    for (int j = 0; j < NR; j++) {
        const float4 v = ((const float4*)(v_init + (size_t)j * TT))[t4];
#pragma unroll
        for (int g = 0; g < 5; g++) {
            const float a = A[(size_t)j * NR + i0 + g];
            acc[g].x = fmaf(a, v.x, acc[g].x); acc[g].y = fmaf(a, v.y, acc[g].y);
            acc[g].z = fmaf(a, v.z, acc[g].z); acc[g].w = fmaf(a, v.w, acc[g].w);
        }
    }
#pragma unroll
    for (int g = 0; g < 5; g++) {
        const float4 p = ((const float4*)(inp + (size_t)(i0 + g) * TT))[t4];
        float4 r;
        r.x = p.x + acc[g].x; r.y = p.y + acc[g].y;
        r.z = p.z + acc[g].z; r.w = p.w + acc[g].w;
        ((float4*)(X + (size_t)(i0 + g) * TT))[t4] = r;
    }
}

// ---------------- persistent chain: whole 300-region sequence in ONE kernel ----------------
// grid = 240 blocks x 256 threads (1/CU, all resident; spin-safe).
// KEY R13 change: W slice and state scalars are FORCE-MATERIALIZED into VGPRs
// in the idle window (pin()). R12's VGPR_Count=124 proved the compiler sank
// the 128 W loads into the GEMM loop -> W streamed from memory on the critical
// path after the sync. Now the GEMM is pure LDS+VALU.
__global__ __launch_bounds__(256, 1) void k_chain(
    const float* __restrict__ W,   const float* __restrict__ vb0,
    const float* __restrict__ va0, const float* __restrict__ A,
    const float* __restrict__ v_init, const float* __restrict__ X,
    const float* __restrict__ rbar0,  const float* __restrict__ ebar0,
    float* __restrict__ delta, int* __restrict__ flagmat,
    float* __restrict__ out_sp, float* __restrict__ outW,
    double* __restrict__ fpart) {

    const int tid  = threadIdx.x;
    const int lane = tid & 63;
    const int wv   = tid >> 6;
    const int rb   = blockIdx.x >> 3;
    const int qq   = blockIdx.x & 7;
    const int k_local = tid >> 2;        // 0..63
    const int mq   = tid & 3;            // m-quarter AND b-lane
    const int kg   = qq * 64 + k_local;  // global output column

    __shared__ __align__(16) float xs[4 * BSTR];
    __shared__ double ps[4];

    const float4* __restrict__ d4 = (const float4*)delta;

    for (int c = 0; c < NCH; c++) {
        const int i = rb + CH * c;
        const size_t base = (size_t)i * TT + (size_t)mq * NN + kg;

        // --- issue W preload + state scalars, then PIN them into VGPRs NOW ---
        float w[128];
        const float* Wp = W + (((size_t)i * NN + (size_t)mq * 128) * NN) + kg;
#pragma unroll
        for (int s = 0; s < 128; s++) w[s] = Wp[(size_t)s * NN];
        float vb0v = vb0[base];
        float va0v = va0[base];
        float vsi  = v_init[base];
        float eb0v = ebar0[base];
#pragma unroll
        for (int s = 0; s < 128; s++) pin(w[s]);
        pin(vb0v); pin(va0v); pin(vsi); pin(eb0v);

        float4 r0 = ((const float4*)(X + (size_t)i * TT))[tid];
        float4 r1 = ((const float4*)(X + (size_t)i * TT))[tid + 256];

        int jdone = 0;
        if (i > 0) {
            // --- bulk: flag-gated plain pipelined float4 gather, tiered backoff ---
            for (;;) {
                int v = (lane < 32)
                    ? __hip_atomic_load(&flagmat[i * 32 + lane], __ATOMIC_RELAXED, __HIP_MEMORY_SCOPE_AGENT)
                    : 0x7fffffff;
                v = min(v, __shfl_xor(v, 1));
                v = min(v, __shfl_xor(v, 2));
                v = min(v, __shfl_xor(v, 4));
                v = min(v, __shfl_xor(v, 8));
                v = min(v, __shfl_xor(v, 16));
                int r = __shfl(v, 0);
                if (r > i) r = i;
                const bool prog = (r > jdone);
                if (prog) {
                    asm volatile("" ::: "memory");
                    for (int j = jdone; j < r; j++) {
                        const float a = A[(size_t)j * NR + i];
                        const float4 d0 = d4[j * 512 + tid];
                        const float4 d1 = d4[j * 512 + tid + 256];
                        r0.x = fmaf(a, d0.x, r0.x); r0.y = fmaf(a, d0.y, r0.y);
                        r0.z = fmaf(a, d0.z, r0.z); r0.w = fmaf(a, d0.w, r0.w);
                        r1.x = fmaf(a, d1.x, r1.x); r1.y = fmaf(a, d1.y, r1.y);
                        r1.z = fmaf(a, d1.z, r1.z); r1.w = fmaf(a, d1.w, r1.w);
                    }
                    jdone = r;
                }
                const int dist = i - jdone;
                if (dist <= 4) break;
                if (!prog) {
                    if (dist > 24)      __builtin_amdgcn_s_sleep(32);
                    else if (dist > 10) __builtin_amdgcn_s_sleep(8);
                    else                __builtin_amdgcn_s_sleep(1);
                }
            }
            // --- tail (<=4 regions): two-stream sentinel poll; A-coeffs preloaded ---
            const int n = i - jdone;
            if (n > 0) {
                const int jc1 = min(jdone + 1, i - 1);
                const int jc2 = min(jdone + 2, i - 1);
                const int jc3 = min(jdone + 3, i - 1);
                const float aj0 = A[(size_t)jdone * NR + i];
                const float aj1 = A[(size_t)jc1 * NR + i];
                const float aj2 = A[(size_t)jc2 * NR + i];
                const float aj3 = A[(size_t)jc3 * NR + i];
#define TCONS(K, JK, AJ)                                                        \
                if (K < n) {                                                    \
                    const float* p0 = delta + (size_t)(JK) * TT + 4 * tid;      \
                    float o0,o1,o2,o3,o4,o5,o6,o7;                              \
                    poll8_2s(p0, p0 + 1024, o0,o1,o2,o3,o4,o5,o6,o7);           \
                    r0.x = fmaf(AJ, o0, r0.x); r0.y = fmaf(AJ, o1, r0.y);       \
                    r0.z = fmaf(AJ, o2, r0.z); r0.w = fmaf(AJ, o3, r0.w);       \
                    r1.x = fmaf(AJ, o4, r1.x); r1.y = fmaf(AJ, o5, r1.y);       \
                    r1.z = fmaf(AJ, o6, r1.z); r1.w = fmaf(AJ, o7, r1.w);       \
                }
                TCONS(0, jdone, aj0)
                TCONS(1, jc1, aj1)
                TCONS(2, jc2, aj2)
                TCONS(3, jc3, aj3)
#undef TCONS
            }
        }

        // --- publish x into LDS (float4-aligned in padded layout), one barrier ---
        {
            const int e0 = 4 * tid;
            const int e1 = 4 * tid + 1024;
            *(float4*)&xs[xidx(e0 >> 9, e0 & 511)] = r0;
            *(float4*)&xs[xidx(e1 >> 9, e1 & 511)] = r1;
        }
        __syncthreads();

        // --- GEMM: pred[b][kg] = sum_m x[b][m]*W[m][kg]; pure LDS+VALU now ---
        float acc0 = 0.f, acc1 = 0.f, acc2 = 0.f, acc3 = 0.f;
#pragma unroll
        for (int s4 = 0; s4 < 32; s4++) {
            const int mb = mq * QSTR + s4 * 4;
            float4 x0 = *(const float4*)&xs[mb];
            float4 x1 = *(const float4*)&xs[BSTR + mb];
            float4 x2 = *(const float4*)&xs[2 * BSTR + mb];
            float4 x3 = *(const float4*)&xs[3 * BSTR + mb];
            const float w0 = w[s4 * 4], w1 = w[s4 * 4 + 1], w2 = w[s4 * 4 + 2], w3 = w[s4 * 4 + 3];
            acc0 += x0.x * w0 + x0.y * w1 + x0.z * w2 + x0.w * w3;
            acc1 += x1.x * w0 + x1.y * w1 + x1.z * w2 + x1.w * w3;
            acc2 += x2.x * w0 + x2.y * w1 + x2.z * w2 + x2.w * w3;
            acc3 += x3.x * w0 + x3.y * w1 + x3.z * w2 + x3.w * w3;
        }
        acc0 += __shfl_xor(acc0, 1); acc0 += __shfl_xor(acc0, 2);
        acc1 += __shfl_xor(acc1, 1); acc1 += __shfl_xor(acc1, 2);
        acc2 += __shfl_xor(acc2, 1); acc2 += __shfl_xor(acc2, 2);
        acc3 += __shfl_xor(acc3, 1); acc3 += __shfl_xor(acc3, 2);
        const float pred = (mq == 0) ? acc0 : (mq == 1) ? acc1 : (mq == 2) ? acc2 : acc3;

        // --- state update; delta sc1 store FIRST (the signal) ---
        const float vb  = TAU * vb0v + OMT * pred;
        const float va  = TAU * va0v;
        const float vs  = TAU * vsi + OMT * (vb - va);
        __hip_atomic_store(&delta[base], vs - vsi, __ATOMIC_RELAXED, __HIP_MEMORY_SCOPE_AGENT);
        const float mis = vs - vb;

        // --- lazy flag publish (bulk-path hint; off reader critical path) ---
        asm volatile("s_waitcnt vmcnt(0)" ::: "memory");   // delta in IC before flag
        {
            const int slot = (qq << 2) + wv;
            for (int r = i + 1 + lane; r < NR; r += 64)
                __hip_atomic_store(&flagmat[r * 32 + slot], i + 1,
                                   __ATOMIC_RELAXED, __HIP_MEMORY_SCOPE_AGENT);
        }
        out_sp[base] = (vs > 0.f) ? 1.f : 0.f;
        __syncthreads();   // protect xs: GEMM reads done before rbar overwrite

        // --- fused Hebbian (off critical path): rbar in-place into xs, float4 ---
#pragma unroll
        for (int s = 0; s < 2; s++) {
            const int e = 4 * tid + s * 1024;
            float* xp = &xs[xidx(e >> 9, e & 511)];
            const float4 rr = ((const float4*)(rbar0 + (size_t)i * TT))[tid + s * 256];
            float4 xv = *(float4*)xp;
            xv.x = OMA * rr.x + ALPH * xv.x; xv.y = OMA * rr.y + ALPH * xv.y;
            xv.z = OMA * rr.z + ALPH * xv.z; xv.w = OMA * rr.w + ALPH * xv.w;
            *(float4*)xp = xv;
        }
        __syncthreads();

        const float e_own = OMA * eb0v + ALPH * mis;
        const int qb = lane & ~3;
        const float e0 = __shfl(e_own, qb + 0);
        const float e1 = __shfl(e_own, qb + 1);
        const float e2 = __shfl(e_own, qb + 2);
        const float e3 = __shfl(e_own, qb + 3);

        // vectorized LDS reads (same per-element expression tree), PLAIN stores
#pragma unroll
        for (int s4 = 0; s4 < 32; s4++) {
            const int xo = mq * QSTR + s4 * 4;
            const float4 X0 = *(const float4*)&xs[xo];
            const float4 X1 = *(const float4*)&xs[BSTR + xo];
            const float4 X2 = *(const float4*)&xs[2 * BSTR + xo];
            const float4 X3 = *(const float4*)&xs[3 * BSTR + xo];
            const int m0 = mq * 128 + s4 * 4;
            float* op = &outW[(((size_t)i * NN + m0) * NN) + kg];
            op[0]    = w[s4*4+0] + LRQ * (e0*X0.x + e1*X1.x + e2*X2.x + e3*X3.x);
            op[NN]   = w[s4*4+1] + LRQ * (e0*X0.y + e1*X1.y + e2*X2.y + e3*X3.y);
            op[2*NN] = w[s4*4+2] + LRQ * (e0*X0.z + e1*X1.z + e2*X2.z + e3*X3.z);
            op[3*NN] = w[s4*4+3] + LRQ * (e0*X0.w + e1*X1.w + e2*X2.w + e3*X3.w);
        }

        // --- F partial (deterministic per-block double) ---
        double p = (double)mis * (double)mis;
#pragma unroll
        for (int off = 32; off; off >>= 1) p += __shfl_xor(p, off);
        if (lane == 0) ps[wv] = p;
        __syncthreads();
        if (tid == 0) fpart[(size_t)i * SLC + qq] = ps[0] + ps[1] + ps[2] + ps[3];
        __syncthreads();   // ps consumed before next iteration rewrites it
    }
}

// ---------------- final F reduction ----------------
__global__ __launch_bounds__(256) void k_fin(const double* __restrict__ fpart,
                                             float* __restrict__ outF) {
    __shared__ double ps[256];
    double s = 0.0;
    for (int idx = threadIdx.x; idx < NR * SLC; idx += 256) s += fpart[idx];
    ps[threadIdx.x] = s;
    __syncthreads();
    for (int st = 128; st; st >>= 1) {
        if (threadIdx.x < st) ps[threadIdx.x] += ps[threadIdx.x + st];
        __syncthreads();
    }
    if (threadIdx.x == 0) outF[0] = (float)(ps[0] / 614400.0);
}

extern "C" void kernel_launch(void* const* d_in, const int* in_sizes, int n_in,
                              void* d_out, int out_size, void* d_ws, size_t ws_size,
                              hipStream_t stream) {
    const float* v_s0  = (const float*)d_in[0];
    const float* v_b0  = (const float*)d_in[1];
    const float* v_a0  = (const float*)d_in[2];
    const float* rbar0 = (const float*)d_in[3];
    const float* ebar0 = (const float*)d_in[4];
    const float* W     = (const float*)d_in[5];
    const float* A     = (const float*)d_in[6];
    const float* inp   = (const float*)d_in[7];
    const float* noise = (const float*)d_in[8];

    float* out_sp = (float*)d_out;                 // [300,4,512]
    float* out_W  = out_sp + 614400;               // [300,512,512]
    float* out_F  = out_sp + 79257600;             // scalar

    char* ws = (char*)d_ws;
    float* v_init  = (float*)ws;                       // 614400 f
    float* X       = v_init + 614400;                  // 614400 f
    float* delta   = X + 614400;                       // 614400 f @ byte 4915200
    int*   flagmat = (int*)(ws + 7372800);             // 300 rows x 32 ints (128B rows)
    double* fpart  = (double*)(ws + 7411200);          // 2400 doubles

    // one memset covers delta sentinel (0xFFFFFFFF = NaN) AND flagmat (-1)
    (void)hipMemsetAsync(delta, 0xFF, 2457600 + NR * 32 * sizeof(int), stream);
    k_init<<<600, 256, 0, stream>>>(v_s0, noise, v_init);
    k_base<<<120, 256, 0, stream>>>(A, v_init, inp, X);
    k_chain<<<CH * SLC, 256, 0, stream>>>(W, v_b0, v_a0, A, v_init, X,
                                          rbar0, ebar0, delta, flagmat,
                                          out_sp, out_W, fpart);
    k_fin<<<1, 256, 0, stream>>>(fpart, out_F);
}

// Round 14
// 1239.984 us; speedup vs baseline: 1.0283x; 1.0283x over previous
//
#include <hip/hip_runtime.h>

// Problem constants
#define NR   300
#define NB   4
#define NN   512
#define TT   2048          // NB*NN
#define CH   30            // region-row stride (persistent blocks)
#define NCH  10            // regions per block
#define SLC  8             // k-slice blocks per region (64 cols each)

#define TAU   0.8f
#define OMT   0.2f         // 1-TAU
#define ALPH  0.05f
#define OMA   0.95f
#define LRQ   5.0e-6f      // HEBB_LR / B = 2e-5/4
#define NSC   0.02f

#define SENT  0xFFFFFFFFu  // delta sentinel (negative qNaN; vs-vsi always finite)

// padded LDS x layout: [b][quarter][128] with quarter stride 136 floats
#define QSTR 136
#define BSTR 544           // 4*136
__device__ __forceinline__ int xidx(int b, int n) {
    return b * BSTR + (n >> 7) * QSTR + (n & 127);
}

// ---- TWO-STREAM sentinel poll, fully self-contained in one asm block.
// Stream buffers are hard-clobbered v[32:47] (never C++-visible -> no
// spill-before-wait hazard, R8 lesson). Streams staggered ~RT/2 by s_sleep.
__device__ __forceinline__ void poll8_2s(const float* p0, const float* p1,
                                         float& o0, float& o1, float& o2, float& o3,
                                         float& o4, float& o5, float& o6, float& o7) {
    unsigned long long sacc;
    asm volatile(
        "global_load_dwordx4 v[32:35], %9, off sc0 sc1\n\t"
        "global_load_dwordx4 v[36:39], %10, off sc0 sc1\n\t"
        "s_sleep 5\n\t"
        "global_load_dwordx4 v[40:43], %9, off sc0 sc1\n\t"
        "global_load_dwordx4 v[44:47], %10, off sc0 sc1\n\t"
        "Lpoll_%=:\n\t"
        "s_waitcnt vmcnt(2)\n\t"
        "v_cmp_ne_u32 vcc, -1, v32\n\t"
        "s_mov_b64 %8, vcc\n\t"
        "v_cmp_ne_u32 vcc, -1, v33\n\t"
        "s_and_b64 %8, %8, vcc\n\t"
        "v_cmp_ne_u32 vcc, -1, v34\n\t"
        "s_and_b64 %8, %8, vcc\n\t"
        "v_cmp_ne_u32 vcc, -1, v35\n\t"
        "s_and_b64 %8, %8, vcc\n\t"
        "v_cmp_ne_u32 vcc, -1, v36\n\t"
        "s_and_b64 %8, %8, vcc\n\t"
        "v_cmp_ne_u32 vcc, -1, v37\n\t"
        "s_and_b64 %8, %8, vcc\n\t"
        "v_cmp_ne_u32 vcc, -1, v38\n\t"
        "s_and_b64 %8, %8, vcc\n\t"
        "v_cmp_ne_u32 vcc, -1, v39\n\t"
        "s_and_b64 %8, %8, vcc\n\t"
        "s_cmp_eq_u64 %8, exec\n\t"
        "s_cbranch_scc1 Ldone0_%=\n\t"
        "global_load_dwordx4 v[32:35], %9, off sc0 sc1\n\t"
        "global_load_dwordx4 v[36:39], %10, off sc0 sc1\n\t"
        "s_waitcnt vmcnt(2)\n\t"
        "v_cmp_ne_u32 vcc, -1, v40\n\t"
        "s_mov_b64 %8, vcc\n\t"
        "v_cmp_ne_u32 vcc, -1, v41\n\t"
        "s_and_b64 %8, %8, vcc\n\t"
        "v_cmp_ne_u32 vcc, -1, v42\n\t"
        "s_and_b64 %8, %8, vcc\n\t"
        "v_cmp_ne_u32 vcc, -1, v43\n\t"
        "s_and_b64 %8, %8, vcc\n\t"
        "v_cmp_ne_u32 vcc, -1, v44\n\t"
        "s_and_b64 %8, %8, vcc\n\t"
        "v_cmp_ne_u32 vcc, -1, v45\n\t"
        "s_and_b64 %8, %8, vcc\n\t"
        "v_cmp_ne_u32 vcc, -1, v46\n\t"
        "s_and_b64 %8, %8, vcc\n\t"
        "v_cmp_ne_u32 vcc, -1, v47\n\t"
        "s_and_b64 %8, %8, vcc\n\t"
        "s_cmp_eq_u64 %8, exec\n\t"
        "s_cbranch_scc1 Ldone1_%=\n\t"
        "global_load_dwordx4 v[40:43], %9, off sc0 sc1\n\t"
        "global_load_dwordx4 v[44:47], %10, off sc0 sc1\n\t"
        "s_branch Lpoll_%=\n\t"
        "Ldone1_%=:\n\t"
        "s_waitcnt vmcnt(0)\n\t"
        "v_mov_b32 v32, v40\n\t"
        "v_mov_b32 v33, v41\n\t"
        "v_mov_b32 v34, v42\n\t"
        "v_mov_b32 v35, v43\n\t"
        "v_mov_b32 v36, v44\n\t"
        "v_mov_b32 v37, v45\n\t"
        "v_mov_b32 v38, v46\n\t"
        "v_mov_b32 v39, v47\n\t"
        "Ldone0_%=:\n\t"
        "s_waitcnt vmcnt(0)\n\t"
        "v_mov_b32 %0, v32\n\t"
        "v_mov_b32 %1, v33\n\t"
        "v_mov_b32 %2, v34\n\t"
        "v_mov_b32 %3, v35\n\t"
        "v_mov_b32 %4, v36\n\t"
        "v_mov_b32 %5, v37\n\t"
        "v_mov_b32 %6, v38\n\t"
        "v_mov_b32 %7, v39"
        : "=v"(o0), "=v"(o1), "=v"(o2), "=v"(o3),
          "=v"(o4), "=v"(o5), "=v"(o6), "=v"(o7), "=&s"(sacc)
        : "v"(p0), "v"(p1)
        : "vcc", "memory",
          "v32","v33","v34","v35","v36","v37","v38","v39",
          "v40","v41","v42","v43","v44","v45","v46","v47");
}

// ---------------- v_init = v_s0 + 0.02*noise ----------------
__global__ __launch_bounds__(256) void k_init(const float* __restrict__ vs0,
                                              const float* __restrict__ noise,
                                              float* __restrict__ v_init) {
    int idx = blockIdx.x * 256 + threadIdx.x;           // float4 index
    const float4* a = (const float4*)vs0;
    const float4* b = (const float4*)noise;
    float4* o = (float4*)v_init;
    float4 va = a[idx], vb = b[idx];
    float4 r;
    r.x = va.x + NSC * vb.x; r.y = va.y + NSC * vb.y;
    r.z = va.z + NSC * vb.z; r.w = va.w + NSC * vb.w;
    o[idx] = r;
}

// ---------------- X[i,t] = inp[i,t] + sum_j A[j,i]*v_init[j,t] ----------------
__global__ __launch_bounds__(256) void k_base(const float* __restrict__ A,
                                              const float* __restrict__ v_init,
                                              const float* __restrict__ inp,
                                              float* __restrict__ X) {
    const int i0 = (blockIdx.x >> 1) * 5;
    const int t4 = (blockIdx.x & 1) * 256 + threadIdx.x;   // float4 index 0..511
    float4 acc[5];
#pragma unroll
    for (int g = 0; g < 5; g++) acc[g] = make_float4(0.f, 0.f, 0.f, 0.f);
    for (int j = 0; j < NR; j++) {
        const float4 v = ((const float4*)(v_init + (size_t)j * TT))[t4];
#pragma unroll
        for (int g = 0; g < 5; g++) {
            const float a = A[(size_t)j * NR + i0 + g];
            acc[g].x = fmaf(a, v.x, acc[g].x); acc[g].y = fmaf(a, v.y, acc[g].y);
            acc[g].z = fmaf(a, v.z, acc[g].z); acc[g].w = fmaf(a, v.w, acc[g].w);
        }
    }
#pragma unroll
    for (int g = 0; g < 5; g++) {
        const float4 p = ((const float4*)(inp + (size_t)(i0 + g) * TT))[t4];
        float4 r;
        r.x = p.x + acc[g].x; r.y = p.y + acc[g].y;
        r.z = p.z + acc[g].z; r.w = p.w + acc[g].w;
        ((float4*)(X + (size_t)(i0 + g) * TT))[t4] = r;
    }
}

// ---------------- persistent chain: whole 300-region sequence in ONE kernel ----------------
// grid = 240 blocks x 256 threads (1/CU, all resident; spin-safe).
// R14 change: bulk flag-gated gather consumes through i-2 (threshold dist<=1);
// the tail is EXACTLY ONE two-stream sentinel poll (j = i-1), with its
// A-coefficient preloaded before the bulk loop. Removes ~3 serialized IC RTs
// per step that R12/R13 spent polling already-ready regions.
__global__ __launch_bounds__(256, 1) void k_chain(
    const float* __restrict__ W,   const float* __restrict__ vb0,
    const float* __restrict__ va0, const float* __restrict__ A,
    const float* __restrict__ v_init, const float* __restrict__ X,
    const float* __restrict__ rbar0,  const float* __restrict__ ebar0,
    float* __restrict__ delta, int* __restrict__ flagmat,
    float* __restrict__ out_sp, float* __restrict__ outW,
    double* __restrict__ fpart) {

    const int tid  = threadIdx.x;
    const int lane = tid & 63;
    const int wv   = tid >> 6;
    const int rb   = blockIdx.x >> 3;
    const int qq   = blockIdx.x & 7;
    const int k_local = tid >> 2;        // 0..63
    const int mq   = tid & 3;            // m-quarter AND b-lane
    const int kg   = qq * 64 + k_local;  // global output column

    __shared__ __align__(16) float xs[4 * BSTR];
    __shared__ double ps[4];

    const float4* __restrict__ d4 = (const float4*)delta;

    for (int c = 0; c < NCH; c++) {
        const int i = rb + CH * c;
        const size_t base = (size_t)i * TT + (size_t)mq * NN + kg;

        // --- idle-window preloads: W slice, state scalars, tail A-coeff ---
        float w[128];
        const float* Wp = W + (((size_t)i * NN + (size_t)mq * 128) * NN) + kg;
#pragma unroll
        for (int s = 0; s < 128; s++) w[s] = Wp[(size_t)s * NN];
        float vb0v = vb0[base];
        float va0v = va0[base];
        float vsi  = v_init[base];
        float eb0v = ebar0[base];
        const float aj_last = (i > 0) ? A[(size_t)(i - 1) * NR + i] : 0.f;

        float4 r0 = ((const float4*)(X + (size_t)i * TT))[tid];
        float4 r1 = ((const float4*)(X + (size_t)i * TT))[tid + 256];

        int jdone = 0;
        if (i > 0) {
            // --- bulk: flag-gated plain pipelined float4 gather through i-2 ---
            for (;;) {
                int v = (lane < 32)
                    ? __hip_atomic_load(&flagmat[i * 32 + lane], __ATOMIC_RELAXED, __HIP_MEMORY_SCOPE_AGENT)
                    : 0x7fffffff;
                v = min(v, __shfl_xor(v, 1));
                v = min(v, __shfl_xor(v, 2));
                v = min(v, __shfl_xor(v, 4));
                v = min(v, __shfl_xor(v, 8));
                v = min(v, __shfl_xor(v, 16));
                int r = __shfl(v, 0);
                if (r > i) r = i;
                const bool prog = (r > jdone);
                if (prog) {
                    asm volatile("" ::: "memory");
                    for (int j = jdone; j < r; j++) {
                        const float a = A[(size_t)j * NR + i];
                        const float4 d0 = d4[j * 512 + tid];
                        const float4 d1 = d4[j * 512 + tid + 256];
                        r0.x = fmaf(a, d0.x, r0.x); r0.y = fmaf(a, d0.y, r0.y);
                        r0.z = fmaf(a, d0.z, r0.z); r0.w = fmaf(a, d0.w, r0.w);
                        r1.x = fmaf(a, d1.x, r1.x); r1.y = fmaf(a, d1.y, r1.y);
                        r1.z = fmaf(a, d1.z, r1.z); r1.w = fmaf(a, d1.w, r1.w);
                    }
                    jdone = r;
                }
                const int dist = i - jdone;
                if (dist <= 1) break;
                if (!prog) {                 // no progress: back off by distance
                    if (dist > 24)      __builtin_amdgcn_s_sleep(32);
                    else if (dist > 10) __builtin_amdgcn_s_sleep(8);
                    else if (dist > 2)  __builtin_amdgcn_s_sleep(1);
                    // dist == 2: hot flag poll (i-2's flag arrives ~2 RT after
                    // its delta; catch it immediately)
                }
            }
            // --- tail: single two-stream sentinel poll for j = i-1 ---
            if (jdone < i) {
                const float* p0 = delta + (size_t)(i - 1) * TT + 4 * tid;
                float o0,o1,o2,o3,o4,o5,o6,o7;
                poll8_2s(p0, p0 + 1024, o0,o1,o2,o3,o4,o5,o6,o7);
                r0.x = fmaf(aj_last, o0, r0.x); r0.y = fmaf(aj_last, o1, r0.y);
                r0.z = fmaf(aj_last, o2, r0.z); r0.w = fmaf(aj_last, o3, r0.w);
                r1.x = fmaf(aj_last, o4, r1.x); r1.y = fmaf(aj_last, o5, r1.y);
                r1.z = fmaf(aj_last, o6, r1.z); r1.w = fmaf(aj_last, o7, r1.w);
            }
        }

        // --- publish x into LDS (float4-aligned in padded layout), one barrier ---
        {
            const int e0 = 4 * tid;
            const int e1 = 4 * tid + 1024;
            *(float4*)&xs[xidx(e0 >> 9, e0 & 511)] = r0;
            *(float4*)&xs[xidx(e1 >> 9, e1 & 511)] = r1;
        }
        __syncthreads();

        // --- GEMM: pred[b][kg] = sum_m x[b][m]*W[m][kg]; chains identical to R13 ---
        float acc0 = 0.f, acc1 = 0.f, acc2 = 0.f, acc3 = 0.f;
#pragma unroll
        for (int s4 = 0; s4 < 32; s4++) {
            const int mb = mq * QSTR + s4 * 4;
            float4 x0 = *(const float4*)&xs[mb];
            float4 x1 = *(const float4*)&xs[BSTR + mb];
            float4 x2 = *(const float4*)&xs[2 * BSTR + mb];
            float4 x3 = *(const float4*)&xs[3 * BSTR + mb];
            const float w0 = w[s4 * 4], w1 = w[s4 * 4 + 1], w2 = w[s4 * 4 + 2], w3 = w[s4 * 4 + 3];
            acc0 += x0.x * w0 + x0.y * w1 + x0.z * w2 + x0.w * w3;
            acc1 += x1.x * w0 + x1.y * w1 + x1.z * w2 + x1.w * w3;
            acc2 += x2.x * w0 + x2.y * w1 + x2.z * w2 + x2.w * w3;
            acc3 += x3.x * w0 + x3.y * w1 + x3.z * w2 + x3.w * w3;
        }
        acc0 += __shfl_xor(acc0, 1); acc0 += __shfl_xor(acc0, 2);
        acc1 += __shfl_xor(acc1, 1); acc1 += __shfl_xor(acc1, 2);
        acc2 += __shfl_xor(acc2, 1); acc2 += __shfl_xor(acc2, 2);
        acc3 += __shfl_xor(acc3, 1); acc3 += __shfl_xor(acc3, 2);
        const float pred = (mq == 0) ? acc0 : (mq == 1) ? acc1 : (mq == 2) ? acc2 : acc3;

        // --- state update; delta sc1 store FIRST (the signal) ---
        const float vb  = TAU * vb0v + OMT * pred;
        const float va  = TAU * va0v;
        const float vs  = TAU * vsi + OMT * (vb - va);
        __hip_atomic_store(&delta[base], vs - vsi, __ATOMIC_RELAXED, __HIP_MEMORY_SCOPE_AGENT);
        const float mis = vs - vb;

        // --- lazy flag publish (bulk-path hint; off reader critical path) ---
        asm volatile("s_waitcnt vmcnt(0)" ::: "memory");   // delta in IC before flag
        {
            const int slot = (qq << 2) + wv;
            for (int r = i + 1 + lane; r < NR; r += 64)
                __hip_atomic_store(&flagmat[r * 32 + slot], i + 1,
                                   __ATOMIC_RELAXED, __HIP_MEMORY_SCOPE_AGENT);
        }
        out_sp[base] = (vs > 0.f) ? 1.f : 0.f;
        __syncthreads();   // protect xs: GEMM reads done before rbar overwrite

        // --- fused Hebbian (off critical path): rbar in-place into xs, float4 ---
#pragma unroll
        for (int s = 0; s < 2; s++) {
            const int e = 4 * tid + s * 1024;
            float* xp = &xs[xidx(e >> 9, e & 511)];
            const float4 rr = ((const float4*)(rbar0 + (size_t)i * TT))[tid + s * 256];
            float4 xv = *(float4*)xp;
            xv.x = OMA * rr.x + ALPH * xv.x; xv.y = OMA * rr.y + ALPH * xv.y;
            xv.z = OMA * rr.z + ALPH * xv.z; xv.w = OMA * rr.w + ALPH * xv.w;
            *(float4*)xp = xv;
        }
        __syncthreads();

        const float e_own = OMA * eb0v + ALPH * mis;
        const int qb = lane & ~3;
        const float e0 = __shfl(e_own, qb + 0);
        const float e1 = __shfl(e_own, qb + 1);
        const float e2 = __shfl(e_own, qb + 2);
        const float e3 = __shfl(e_own, qb + 3);

        // vectorized LDS reads (same per-element expression tree), PLAIN stores
#pragma unroll
        for (int s4 = 0; s4 < 32; s4++) {
            const int xo = mq * QSTR + s4 * 4;
            const float4 X0 = *(const float4*)&xs[xo];
            const float4 X1 = *(const float4*)&xs[BSTR + xo];
            const float4 X2 = *(const float4*)&xs[2 * BSTR + xo];
            const float4 X3 = *(const float4*)&xs[3 * BSTR + xo];
            const int m0 = mq * 128 + s4 * 4;
            float* op = &outW[(((size_t)i * NN + m0) * NN) + kg];
            op[0]    = w[s4*4+0] + LRQ * (e0*X0.x + e1*X1.x + e2*X2.x + e3*X3.x);
            op[NN]   = w[s4*4+1] + LRQ * (e0*X0.y + e1*X1.y + e2*X2.y + e3*X3.y);
            op[2*NN] = w[s4*4+2] + LRQ * (e0*X0.z + e1*X1.z + e2*X2.z + e3*X3.z);
            op[3*NN] = w[s4*4+3] + LRQ * (e0*X0.w + e1*X1.w + e2*X2.w + e3*X3.w);
        }

        // --- F partial (deterministic per-block double) ---
        double p = (double)mis * (double)mis;
#pragma unroll
        for (int off = 32; off; off >>= 1) p += __shfl_xor(p, off);
        if (lane == 0) ps[wv] = p;
        __syncthreads();
        if (tid == 0) fpart[(size_t)i * SLC + qq] = ps[0] + ps[1] + ps[2] + ps[3];
        __syncthreads();   // ps consumed before next iteration rewrites it
    }
}

// ---------------- final F reduction ----------------
__global__ __launch_bounds__(256) void k_fin(const double* __restrict__ fpart,
                                             float* __restrict__ outF) {
    __shared__ double ps[256];
    double s = 0.0;
    for (int idx = threadIdx.x; idx < NR * SLC; idx += 256) s += fpart[idx];
    ps[threadIdx.x] = s;
    __syncthreads();
    for (int st = 128; st; st >>= 1) {
        if (threadIdx.x < st) ps[threadIdx.x] += ps[threadIdx.x + st];
        __syncthreads();
    }
    if (threadIdx.x == 0) outF[0] = (float)(ps[0] / 614400.0);
}

extern "C" void kernel_launch(void* const* d_in, const int* in_sizes, int n_in,
                              void* d_out, int out_size, void* d_ws, size_t ws_size,
                              hipStream_t stream) {
    const float* v_s0  = (const float*)d_in[0];
    const float* v_b0  = (const float*)d_in[1];
    const float* v_a0  = (const float*)d_in[2];
    const float* rbar0 = (const float*)d_in[3];
    const float* ebar0 = (const float*)d_in[4];
    const float* W     = (const float*)d_in[5];
    const float* A     = (const float*)d_in[6];
    const float* inp   = (const float*)d_in[7];
    const float* noise = (const float*)d_in[8];

    float* out_sp = (float*)d_out;                 // [300,4,512]
    float* out_W  = out_sp + 614400;               // [300,512,512]
    float* out_F  = out_sp + 79257600;             // scalar

    char* ws = (char*)d_ws;
    float* v_init  = (float*)ws;                       // 614400 f
    float* X       = v_init + 614400;                  // 614400 f
    float* delta   = X + 614400;                       // 614400 f @ byte 4915200
    int*   flagmat = (int*)(ws + 7372800);             // 300 rows x 32 ints (128B rows)
    double* fpart  = (double*)(ws + 7411200);          // 2400 doubles

    // one memset covers delta sentinel (0xFFFFFFFF = NaN) AND flagmat (-1)
    (void)hipMemsetAsync(delta, 0xFF, 2457600 + NR * 32 * sizeof(int), stream);
    k_init<<<600, 256, 0, stream>>>(v_s0, noise, v_init);
    k_base<<<120, 256, 0, stream>>>(A, v_init, inp, X);
    k_chain<<<CH * SLC, 256, 0, stream>>>(W, v_b0, v_a0, A, v_init, X,
                                          rbar0, ebar0, delta, flagmat,
                                          out_sp, out_W, fpart);
    k_fin<<<1, 256, 0, stream>>>(fpart, out_F);
}